// Round 15
// baseline (2631.110 us; speedup 1.0000x reference)
//
#include <hip/hip_runtime.h>

typedef unsigned short u16;
typedef __attribute__((ext_vector_type(8))) short bf16x8;
typedef __attribute__((ext_vector_type(4))) short bf16x4;
typedef __attribute__((ext_vector_type(4))) float f32x4;
typedef __attribute__((ext_vector_type(4))) unsigned u32x4;
typedef __attribute__((ext_vector_type(2))) unsigned u32x2;

#define DEVINL static __device__ __forceinline__

// bf16 <-> f32 (RNE rounding)
DEVINL u16 f2bf(float x) {
  unsigned u = __float_as_uint(x);
  unsigned r = (u + 0x7FFFu + ((u >> 16) & 1u)) >> 16;
  return (u16)r;
}
DEVINL float bf2f(u16 h) { return __uint_as_float(((unsigned)h) << 16); }

// packed RNE conversion (kept from r14 — null but harmless)
DEVINL unsigned pk2(float lo, float hi) {
  unsigned r;
  asm("v_cvt_pk_bf16_f32 %0, %1, %2" : "=v"(r) : "v"(lo), "v"(hi));
  return r;
}

// async global->LDS, 16B per lane (wave-uniform LDS base + lane*16 pattern)
DEVINL void gload_lds16(const u16* g, u16* l) {
  __builtin_amdgcn_global_load_lds(
      (const __attribute__((address_space(1))) void*)g,
      (__attribute__((address_space(3))) void*)l, 16, 0, 0);
}

// Row-pair granule swizzle for a [256 rows][32 cols] bf16 operand tile.
// Verified zero bank conflicts on HW (r6: SQ_LDS_BANK_CONFLICT 6.3M -> 0).
DEVINL int swzg(int r, int s) {
  return ((r >> 1) << 3) + ((((r & 1) << 2) | s) ^ ((r >> 1) & 7));
}
// granule -> logical (row, kslot)
DEVINL void g2rk(int g, int& row, int& ks) {
  int p = g >> 3, w = (g & 7) ^ (p & 7);
  row = p * 2 + (w >> 2);
  ks = w & 3;
}

// Stage one bf16 operand tile [256][32] into LDS (2 gload instr per thread).
DEVINL void stage_half(const u16* gbase, int K, u16* ldst, int tid) {
#pragma unroll
  for (int i = 0; i < 2; i++) {
    int g = i * 512 + tid;
    int row, ks;
    g2rk(g, row, ks);
    gload_lds16(gbase + (size_t)row * K + ks * 8, ldst + g * 8);
  }
}

// load 8 f32 + packed-cvt -> one 16B LDS granule write
DEVINL void cvt_write_granule(const float* src, u16* dst) {
  f32x4 a = *(const f32x4*)src;
  f32x4 b = *(const f32x4*)(src + 4);
  u32x4 w;
  w[0] = pk2(a[0], a[1]);
  w[1] = pk2(a[2], a[3]);
  w[2] = pk2(b[0], b[1]);
  w[3] = pk2(b[2], b[3]);
  *(u32x4*)dst = w;
}

// ---------------------------------------------------------------------------
// GEMM: C[M,N] = scale*(A[M,K] * B[N,K]^T bf16) [+bias] [+resid]
// r15 STRUCTURAL CHANGE: 2-buffer LDS (64 KB) -> 2 blocks/CU (was 3-buf
// 96 KB -> 1 block/CU, OccupancyPercent 19.7, MfmaUtil 34.6 -- lockstep
// stall). Drain ledger: stage t+1 into the other buffer during compute(t)
// (WAR-safe: its reads finished before the barrier admitting t); boundary
// vmcnt(0) [lgkmcnt(0) for A_F32 ds_writes] + one barrier. The per-block
// drain is covered by the co-resident block's MFMA (m97/m114 mechanism).
// A_F32: fused fp32->bf16 cvt in A-staging (same-iteration r8 scheme).
// TRANSV / SMODE 1 / SMODE 2 epilogues unchanged (r13-verified).
// ---------------------------------------------------------------------------
template <bool A_F32, bool HAS_BIAS, bool RESID, bool OUT_F32, bool TRANSV,
          int SMODE>
__global__ __launch_bounds__(512, 4) void gemm_bt(
    const void* __restrict__ Ap_, const u16* __restrict__ Bp,
    const float* __restrict__ bias, const float* __restrict__ resid,
    float* __restrict__ rsum, void* __restrict__ Cp, int N, int K,
    long long Az, long long Bz, long long Cz, float scale) {
  const int gx = gridDim.x, gy = gridDim.y;
  int lin = blockIdx.x + gx * (blockIdx.y + gy * blockIdx.z);
  const int nwg = gx * gy * gridDim.z;
  if ((nwg & 7) == 0) {
    const int chunk = nwg >> 3;
    lin = (lin & 7) * chunk + (lin >> 3);
  }
  const int bz = lin / (gx * gy);
  const int rem = lin - bz * gx * gy;
  const int m0 = (rem / gx) * 256, n0 = (rem % gx) * 256;

  const int tid = threadIdx.x, lane = tid & 63, wv = tid >> 6;
  const int wr = wv >> 2, wc = wv & 3, lr = lane & 15, lh = lane >> 4;

  // 2 bufs x (A 16KB + B 16KB) = 64 KB -> 2 blocks/CU
  __shared__ u16 lds[2 * 16384];

  const u16* A16 = nullptr;
  const float* A32 = nullptr;
  if constexpr (A_F32)
    A32 = (const float*)Ap_ + (size_t)bz * Az + (size_t)m0 * K;
  else
    A16 = (const u16*)Ap_ + (size_t)bz * Az + (size_t)m0 * K;
  const u16* B = Bp + (size_t)bz * Bz + (size_t)n0 * K;

  f32x4 acc[8][4] = {};
  const int nt = K >> 5;

  // ---- prologue: tile 0 resident in buf0 ----
  if constexpr (A_F32) {
#pragma unroll
    for (int i = 0; i < 2; i++) {
      int g = i * 512 + tid, row, ks;
      g2rk(g, row, ks);
      cvt_write_granule(A32 + (size_t)row * K + ks * 8, &lds[g * 8]);
    }
    stage_half(B, K, &lds[8192], tid);
    asm volatile("s_waitcnt vmcnt(0) lgkmcnt(0)" ::: "memory");
  } else {
    stage_half(A16, K, &lds[0], tid);
    stage_half(B, K, &lds[8192], tid);
    asm volatile("s_waitcnt vmcnt(0)" ::: "memory");
  }
  __builtin_amdgcn_s_barrier();

  for (int t = 0; t < nt; ++t) {
    const u16* la = &lds[(t & 1) * 16384];
    const u16* lb = la + 8192;
    u16* nbuf = &lds[((t + 1) & 1) * 16384];
    const bool doPre = (t + 1) < nt;

    // ---- phase 0: B frags + A frags m0..3; issue next-tile A ----
    bf16x8 bfv[4], af[4];
#pragma unroll
    for (int n = 0; n < 4; n++) {
      int row = wc * 64 + n * 16 + lr;
      bfv[n] = *(const bf16x8*)&lb[swzg(row, lh) * 8];
    }
#pragma unroll
    for (int m = 0; m < 4; m++) {
      int row = wr * 128 + m * 16 + lr;
      af[m] = *(const bf16x8*)&la[swzg(row, lh) * 8];
    }
    f32x4 pre0, pre1;
    if constexpr (A_F32) {
      if (doPre) {  // granule 0 of A(t+1): issue early, consume in phase 1
        int row, ks;
        g2rk(tid, row, ks);
        const float* src = A32 + (size_t)row * K + (t + 1) * 32 + ks * 8;
        pre0 = *(const f32x4*)src;
        pre1 = *(const f32x4*)(src + 4);
      }
    } else {
      if (doPre) stage_half(A16 + (size_t)(t + 1) * 32, K, nbuf, tid);
    }
    __builtin_amdgcn_s_setprio(1);
#pragma unroll
    for (int m = 0; m < 4; m++)
#pragma unroll
      for (int n = 0; n < 4; n++)
        acc[m][n] = __builtin_amdgcn_mfma_f32_16x16x32_bf16(af[m], bfv[n],
                                                            acc[m][n], 0, 0, 0);
    __builtin_amdgcn_s_setprio(0);

    // ---- phase 1: A frags m4..7; stage B(t+1); A_F32: cvt+ds_write ----
#pragma unroll
    for (int m = 0; m < 4; m++) {
      int row = wr * 128 + (m + 4) * 16 + lr;
      af[m] = *(const bf16x8*)&la[swzg(row, lh) * 8];
    }
    if (doPre) stage_half(B + (size_t)(t + 1) * 32, K, nbuf + 8192, tid);
    if constexpr (A_F32) {
      if (doPre) {
        u32x4 w0;
        w0[0] = pk2(pre0[0], pre0[1]);
        w0[1] = pk2(pre0[2], pre0[3]);
        w0[2] = pk2(pre1[0], pre1[1]);
        w0[3] = pk2(pre1[2], pre1[3]);
        *(u32x4*)&nbuf[tid * 8] = w0;
        int g = 512 + tid, row, ks;
        g2rk(g, row, ks);
        cvt_write_granule(A32 + (size_t)row * K + (t + 1) * 32 + ks * 8,
                          &nbuf[g * 8]);
      }
    }
    __builtin_amdgcn_s_setprio(1);
#pragma unroll
    for (int m = 0; m < 4; m++)
#pragma unroll
      for (int n = 0; n < 4; n++)
        acc[m + 4][n] = __builtin_amdgcn_mfma_f32_16x16x32_bf16(
            af[m], bfv[n], acc[m + 4][n], 0, 0, 0);
    __builtin_amdgcn_s_setprio(0);

    // ---- tile boundary: drain, one barrier (other block covers stall) ----
    if (doPre) {
      if constexpr (A_F32)
        asm volatile("s_waitcnt vmcnt(0) lgkmcnt(0)" ::: "memory");
      else
        asm volatile("s_waitcnt vmcnt(0)" ::: "memory");
      __builtin_amdgcn_s_barrier();
    }
  }

  // ---- epilogue: C/D layout col=lane&15, row=(lane>>4)*4+reg ----
  if constexpr (TRANSV) {
    // write C^T per 2048-row batch: vhT[b][col][s], s = row % 2048.
    u16* Ch = (u16*)Cp;
#pragma unroll
    for (int m = 0; m < 8; m++) {
      int row0 = m0 + wr * 128 + m * 16 + lh * 4;
      int b = row0 >> 11, s = row0 & 2047;
#pragma unroll
      for (int n = 0; n < 4; n++) {
        int col = n0 + wc * 64 + n * 16 + lr;
        float v0 = acc[m][n][0] * scale, v1 = acc[m][n][1] * scale;
        float v2 = acc[m][n][2] * scale, v3 = acc[m][n][3] * scale;
        if constexpr (HAS_BIAS) {
          float bb = bias[col];
          v0 += bb; v1 += bb; v2 += bb; v3 += bb;
        }
        u32x2 p;
        p[0] = pk2(v0, v1);
        p[1] = pk2(v2, v3);
        *(u32x2*)&Ch[((size_t)b << 21) + ((size_t)col << 11) + s] = p;
      }
    }
  } else if constexpr (SMODE == 1) {
    // scores: write exp(score) bf16 (unnormalized) + deterministic partial
    // row sums: slot = nblk*4 + wc, each [bz][slot][row] written once.
    u16* Ch = (u16*)Cp + (size_t)bz * Cz;
    const int slot = (n0 >> 8) * 4 + wc;  // 0..31
    float* part = rsum + (((size_t)bz * 32 + slot) << 11);
#pragma unroll
    for (int m = 0; m < 8; m++) {
#pragma unroll
      for (int j = 0; j < 4; j++) {
        int row = m0 + wr * 128 + m * 16 + lh * 4 + j;
        float ls = 0.f;
#pragma unroll
        for (int n = 0; n < 4; n++) {
          int col = n0 + wc * 64 + n * 16 + lr;
          float e = __expf(acc[m][n][j] * scale);
          ls += e;
          Ch[(size_t)row * N + col] = f2bf(e);
        }
        // reduce over the 16-lane col group (lane = lh*16 + lr)
        ls += __shfl_xor(ls, 1, 64);
        ls += __shfl_xor(ls, 2, 64);
        ls += __shfl_xor(ls, 4, 64);
        ls += __shfl_xor(ls, 8, 64);
        if (lr == 0) part[row] = ls;  // plain store, L2-resident
      }
    }
  } else {
    float* Cf = nullptr;
    u16* Ch = nullptr;
    if constexpr (OUT_F32)
      Cf = (float*)Cp + (size_t)bz * Cz;
    else
      Ch = (u16*)Cp + (size_t)bz * Cz;
#pragma unroll
    for (int m = 0; m < 8; m++) {
#pragma unroll
      for (int j = 0; j < 4; j++) {
        int row = m0 + wr * 128 + m * 16 + lh * 4 + j;
        float inv = 1.f;
        if constexpr (SMODE == 2) inv = 1.0f / rsum[((size_t)bz << 11) + row];
#pragma unroll
        for (int n = 0; n < 4; n++) {
          int col = n0 + wc * 64 + n * 16 + lr;
          float val = acc[m][n][j] * scale;
          if constexpr (SMODE == 2) val *= inv;
          if constexpr (HAS_BIAS) val += bias[col];
          if constexpr (RESID) val += resid[(size_t)row * N + col];
          if constexpr (OUT_F32)
            Cf[(size_t)row * N + col] = val;
          else
            Ch[(size_t)row * N + col] = f2bf(val);
        }
      }
    }
  }
}

// ---------------------------------------------------------------------------
// fused weight cvt: 4 x [1024x1024] fp32 -> contiguous bf16 (one launch)
// ---------------------------------------------------------------------------
__global__ __launch_bounds__(256) void cvt8w(const float* __restrict__ w0,
                                             const float* __restrict__ w1,
                                             const float* __restrict__ w2,
                                             const float* __restrict__ w3,
                                             u16* __restrict__ out) {
  const int wsel = blockIdx.x >> 9;
  const float* in = wsel == 0 ? w0 : wsel == 1 ? w1 : wsel == 2 ? w2 : w3;
  const size_t i = ((size_t)(blockIdx.x & 511) * 256 + threadIdx.x) * 8;
  f32x4 a = *(const f32x4*)&in[i];
  f32x4 b = *(const f32x4*)&in[i + 4];
  u32x4 w;
  w[0] = pk2(a[0], a[1]);
  w[1] = pk2(a[2], a[3]);
  w[2] = pk2(b[0], b[1]);
  w[3] = pk2(b[2], b[3]);
  *(u32x4*)&out[(size_t)wsel * 1048576 + i] = w;
}

// ---------------------------------------------------------------------------
// fold 32 partial row sums -> rowsum.  part[bz][s][row], coalesced in row.
// ---------------------------------------------------------------------------
__global__ __launch_bounds__(256) void reduce32(const float* __restrict__ part,
                                                float* __restrict__ rowsum) {
  const int g = blockIdx.x * 256 + threadIdx.x;  // 0..16383
  const int bz = g >> 11, r = g & 2047;
  const float* p = part + (((size_t)bz * 32) << 11) + r;
  float s = 0.f;
#pragma unroll
  for (int k = 0; k < 32; k++) s += p[(size_t)k << 11];
  rowsum[g] = s;
}

// ---------------------------------------------------------------------------
// LayerNorm rows of 1024 bf16 -> fp32 d_out  (x stored bf16: halves traffic)
// ---------------------------------------------------------------------------
__global__ __launch_bounds__(256) void ln_rows_bf16(const u16* __restrict__ x,
                                                    const float* __restrict__ gamma,
                                                    const float* __restrict__ beta,
                                                    float* __restrict__ out) {
  const size_t base = (size_t)blockIdx.x * 1024;
  const int tid = threadIdx.x, lane = tid & 63, wv = tid >> 6;
  bf16x4 h4 = *(const bf16x4*)&x[base + tid * 4];
  float v[4];
#pragma unroll
  for (int u = 0; u < 4; u++) v[u] = bf2f((u16)h4[u]);
  float s = v[0] + v[1] + v[2] + v[3];
  float q = v[0] * v[0] + v[1] * v[1] + v[2] * v[2] + v[3] * v[3];
#pragma unroll
  for (int o = 32; o; o >>= 1) {
    s += __shfl_xor(s, o, 64);
    q += __shfl_xor(q, o, 64);
  }
  __shared__ float rs[4], rq[4];
  if (lane == 0) {
    rs[wv] = s;
    rq[wv] = q;
  }
  __syncthreads();
  s = rs[0] + rs[1] + rs[2] + rs[3];
  q = rq[0] + rq[1] + rq[2] + rq[3];
  float mean = s * (1.f / 1024.f);
  float var = q * (1.f / 1024.f) - mean * mean;
  float rstd = rsqrtf(var + 1e-5f);
  f32x4 g = *(const f32x4*)&gamma[tid * 4];
  f32x4 b = *(const f32x4*)&beta[tid * 4];
  f32x4 o;
#pragma unroll
  for (int u = 0; u < 4; u++) o[u] = (v[u] - mean) * rstd * g[u] + b[u];
  *(f32x4*)&out[base + tid * 4] = o;
}

// ---------------------------------------------------------------------------
extern "C" void kernel_launch(void* const* d_in, const int* in_sizes, int n_in,
                              void* d_out, int out_size, void* d_ws,
                              size_t ws_size, hipStream_t stream) {
  (void)in_sizes; (void)n_in; (void)out_size; (void)ws_size;
  const float* q = (const float*)d_in[0];
  const float* k = (const float*)d_in[1];
  const float* v = (const float*)d_in[2];
  const float* Wq = (const float*)d_in[3];
  const float* Wk = (const float*)d_in[4];
  const float* bk = (const float*)d_in[5];
  const float* Wv = (const float*)d_in[6];
  const float* bv = (const float*)d_in[7];
  const float* Wo = (const float*)d_in[8];
  const float* bo = (const float*)d_in[9];
  const float* gamma = (const float*)d_in[10];
  const float* beta = (const float*)d_in[11];
  float* out = (float*)d_out;

  char* ws = (char*)d_ws;
  const size_t SZ_QKV = (size_t)16384 * 1024 * 2;  // 32 MiB
  u16* qh = (u16*)(ws);
  u16* kh = (u16*)(ws + SZ_QKV);
  float* partial = (float*)(ws + 2 * SZ_QKV);            // 2 MB in dead vh slot
  float* rowsum = (float*)(ws + 2 * SZ_QKV + 2097152);   // 64 KB
  u16* vhT = (u16*)(ws + 3 * SZ_QKV);       // [b][1024][2048], written by V-proj
  u16* probs = (u16*)(ws + 4 * SZ_QKV);     // 64 MiB, alive scores->PV
  u16* xbuf = (u16*)(ws + 4 * SZ_QKV);      // bf16 x, overlays probs (dead)
  u16* attn = qh;                           // overlays qh (dead after scores)
  u16* Wqb = (u16*)(ws + 4 * SZ_QKV + (size_t)67108864);
  u16* Wkb = Wqb + 1048576;
  u16* Wvb = Wkb + 1048576;
  u16* Wob = Wvb + 1048576;

  // all 4 weights -> bf16, one launch (dsts contiguous from Wqb)
  cvt8w<<<2048, 256, 0, stream>>>(Wq, Wk, Wv, Wo, Wqb);

  // projections: fp32 A fused-cvt inside GEMM; [16384,1024] x [1024,1024]^T
  dim3 gp(4, 64, 1);  // 256 blocks of 256x256
  gemm_bt<true, false, false, false, false, 0><<<gp, 512, 0, stream>>>(
      q, Wqb, nullptr, nullptr, nullptr, qh, 1024, 1024, 0, 0, 0, 0.125f);
  gemm_bt<true, true, false, false, false, 0><<<gp, 512, 0, stream>>>(
      k, Wkb, bk, nullptr, nullptr, kh, 1024, 1024, 0, 0, 0, 1.0f);
  // V-proj writes vhT directly (transposed epilogue)
  gemm_bt<true, true, false, false, true, 0><<<gp, 512, 0, stream>>>(
      v, Wvb, bv, nullptr, nullptr, vhT, 1024, 1024, 0, 0, 0, 1.0f);

  // scores = exp(qh @ kh^T) per batch -> probs (bf16) + deterministic
  // partial row sums (no atomics); reduce32 folds partials -> rowsum.
  gemm_bt<false, false, false, false, false, 1><<<dim3(8, 8, 8), 512, 0,
                                                  stream>>>(
      qh, kh, nullptr, nullptr, partial, probs, 2048, 1024, 2097152LL,
      2097152LL, 4194304LL, 1.0f);
  reduce32<<<64, 256, 0, stream>>>(partial, rowsum);

  // attn = (probs @ vhT^T) / rowsum per batch
  gemm_bt<false, false, false, false, false, 2><<<dim3(4, 8, 8), 512, 0,
                                                  stream>>>(
      probs, vhT, nullptr, nullptr, rowsum, attn, 1024, 2048, 4194304LL,
      2097152LL, 2097152LL, 1.0f);

  // x = attn @ Wo^T + bo + q  -> bf16 xbuf (halves x traffic; LN reads bf16)
  gemm_bt<false, true, true, false, false, 0><<<dim3(4, 64, 1), 512, 0,
                                                stream>>>(
      attn, Wob, bo, q, nullptr, xbuf, 1024, 1024, 0, 0, 0, 1.0f);

  // LayerNorm -> out
  ln_rows_bf16<<<16384, 256, 0, stream>>>(xbuf, gamma, beta, out);
}

// Round 16
// 402.378 us; speedup vs baseline: 6.5389x; 6.5389x over previous
//
// r16 = exact revert to r14 (best measured, 399.9 us). r15's launch_bounds
// (512,4) capped regs at 128 -> acc[8][4] spilled to scratch (FETCH 49MB ->
// 1.03GB, MfmaUtil 4.8%). 256^2/8-wave tiles are structurally 1-block/CU.
#include <hip/hip_runtime.h>

typedef unsigned short u16;
typedef __attribute__((ext_vector_type(8))) short bf16x8;
typedef __attribute__((ext_vector_type(4))) short bf16x4;
typedef __attribute__((ext_vector_type(4))) float f32x4;
typedef __attribute__((ext_vector_type(4))) unsigned u32x4;
typedef __attribute__((ext_vector_type(2))) unsigned u32x2;

#define DEVINL static __device__ __forceinline__

// bf16 <-> f32 (RNE rounding)
DEVINL u16 f2bf(float x) {
  unsigned u = __float_as_uint(x);
  unsigned r = (u + 0x7FFFu + ((u >> 16) & 1u)) >> 16;
  return (u16)r;
}
DEVINL float bf2f(u16 h) { return __uint_as_float(((unsigned)h) << 16); }

// packed RNE conversion
DEVINL unsigned pk2(float lo, float hi) {
  unsigned r;
  asm("v_cvt_pk_bf16_f32 %0, %1, %2" : "=v"(r) : "v"(lo), "v"(hi));
  return r;
}

// async global->LDS, 16B per lane (wave-uniform LDS base + lane*16 pattern)
DEVINL void gload_lds16(const u16* g, u16* l) {
  __builtin_amdgcn_global_load_lds(
      (const __attribute__((address_space(1))) void*)g,
      (__attribute__((address_space(3))) void*)l, 16, 0, 0);
}

// Row-pair granule swizzle for a [256 rows][32 cols] bf16 operand tile.
// Verified zero bank conflicts on HW (r6: SQ_LDS_BANK_CONFLICT 6.3M -> 0).
DEVINL int swzg(int r, int s) {
  return ((r >> 1) << 3) + ((((r & 1) << 2) | s) ^ ((r >> 1) & 7));
}
// granule -> logical (row, kslot)
DEVINL void g2rk(int g, int& row, int& ks) {
  int p = g >> 3, w = (g & 7) ^ (p & 7);
  row = p * 2 + (w >> 2);
  ks = w & 3;
}

// Stage one bf16 operand tile [256][32] into LDS (2 gload instr per thread).
DEVINL void stage_half(const u16* gbase, int K, u16* ldst, int tid) {
#pragma unroll
  for (int i = 0; i < 2; i++) {
    int g = i * 512 + tid;
    int row, ks;
    g2rk(g, row, ks);
    gload_lds16(gbase + (size_t)row * K + ks * 8, ldst + g * 8);
  }
}

// load 8 f32 + packed-cvt -> one 16B LDS granule write
DEVINL void cvt_write_granule(const float* src, u16* dst) {
  f32x4 a = *(const f32x4*)src;
  f32x4 b = *(const f32x4*)(src + 4);
  u32x4 w;
  w[0] = pk2(a[0], a[1]);
  w[1] = pk2(a[2], a[3]);
  w[2] = pk2(b[0], b[1]);
  w[3] = pk2(b[2], b[3]);
  *(u32x4*)dst = w;
}

// ---------------------------------------------------------------------------
// GEMM: C[M,N] = scale*(A[M,K] * B[N,K]^T bf16) [+bias] [+resid]
// A_F32: fused fp32->bf16 input conversion in A-staging: phase 0 issues
//   granule-0 f32 loads for tile t+2, phase 1 cvt+ds_writes them and
//   inline-loads granule 1. Boundary vmcnt(2) lgkmcnt(0).
// TRANSV: epilogue writes C transposed per 2048-row batch (vhT layout).
// SMODE 1 (scores): epilogue writes exp(scale*acc) bf16 + deterministic
//   partial row sums (plain stores; atomics RMW at coherent point -- r11).
//   reduce32 folds. SMODE 2 (PV): * 1/rsum[row].
// Core (r6, best measured): 256x256 tile, BK=32, 512 thr (8 waves 2Mx4N),
// 3-buffer LDS (96KB), 2-deep prefetch, counted vmcnt, one barrier per
// K-tile, setprio on MFMA, bijective XCD block swizzle. 1 block/CU BY
// DESIGN (r15: forcing 2 blocks/CU spills the 128-reg accumulator).
// ---------------------------------------------------------------------------
template <bool A_F32, bool HAS_BIAS, bool RESID, bool OUT_F32, bool TRANSV,
          int SMODE>
__global__ __launch_bounds__(512, 2) void gemm_bt(
    const void* __restrict__ Ap_, const u16* __restrict__ Bp,
    const float* __restrict__ bias, const float* __restrict__ resid,
    float* __restrict__ rsum, void* __restrict__ Cp, int N, int K,
    long long Az, long long Bz, long long Cz, float scale) {
  const int gx = gridDim.x, gy = gridDim.y;
  int lin = blockIdx.x + gx * (blockIdx.y + gy * blockIdx.z);
  const int nwg = gx * gy * gridDim.z;
  if ((nwg & 7) == 0) {
    const int chunk = nwg >> 3;
    lin = (lin & 7) * chunk + (lin >> 3);
  }
  const int bz = lin / (gx * gy);
  const int rem = lin - bz * gx * gy;
  const int m0 = (rem / gx) * 256, n0 = (rem % gx) * 256;

  const int tid = threadIdx.x, lane = tid & 63, wv = tid >> 6;
  const int wr = wv >> 2, wc = wv & 3, lr = lane & 15, lh = lane >> 4;

  // 3 bufs x (A 16KB + B 16KB) = 96 KB
  __shared__ u16 lds[3 * 16384];

  const u16* A16 = nullptr;
  const float* A32 = nullptr;
  if constexpr (A_F32)
    A32 = (const float*)Ap_ + (size_t)bz * Az + (size_t)m0 * K;
  else
    A16 = (const u16*)Ap_ + (size_t)bz * Az + (size_t)m0 * K;
  const u16* B = Bp + (size_t)bz * Bz + (size_t)n0 * K;

  f32x4 acc[8][4] = {};
  const int nt = K >> 5;

  // ---- prologue: tiles 0,1 resident/staged ----
  if constexpr (A_F32) {
#pragma unroll
    for (int t = 0; t < 2; t++) {
      u16* dstA = &lds[t * 16384];
#pragma unroll
      for (int i = 0; i < 2; i++) {
        int g = i * 512 + tid, row, ks;
        g2rk(g, row, ks);
        cvt_write_granule(A32 + (size_t)row * K + t * 32 + ks * 8,
                          &dstA[g * 8]);
      }
      stage_half(B + t * 32, K, &lds[t * 16384 + 8192], tid);
    }
    asm volatile("s_waitcnt vmcnt(2) lgkmcnt(0)" ::: "memory");
  } else {
    stage_half(A16, K, &lds[0], tid);
    stage_half(B, K, &lds[8192], tid);
    stage_half(A16 + 32, K, &lds[16384], tid);
    stage_half(B + 32, K, &lds[16384 + 8192], tid);
    asm volatile("s_waitcnt vmcnt(4)" ::: "memory");
  }
  __builtin_amdgcn_s_barrier();

  int d = 0;
  for (int t = 0; t < nt; ++t) {
    const u16* la = &lds[d * 16384];
    const u16* lb = la + 8192;
    int dn = d + 2;
    if (dn >= 3) dn -= 3;
    const bool doPre = (t + 2) < nt;

    // ---- phase 0: B frags + A frags m0..3; issue next-A loads / stage A ----
    bf16x8 bfv[4], af[4];
#pragma unroll
    for (int n = 0; n < 4; n++) {
      int row = wc * 64 + n * 16 + lr;
      bfv[n] = *(const bf16x8*)&lb[swzg(row, lh) * 8];
    }
#pragma unroll
    for (int m = 0; m < 4; m++) {
      int row = wr * 128 + m * 16 + lr;
      af[m] = *(const bf16x8*)&la[swzg(row, lh) * 8];
    }
    f32x4 pre0, pre1;
    if constexpr (A_F32) {
      if (doPre) {  // granule 0 of A(t+2): issue early, consume in phase 1
        int row, ks;
        g2rk(tid, row, ks);
        const float* src = A32 + (size_t)row * K + (t + 2) * 32 + ks * 8;
        pre0 = *(const f32x4*)src;
        pre1 = *(const f32x4*)(src + 4);
      }
    } else {
      if (doPre) stage_half(A16 + (size_t)(t + 2) * 32, K, &lds[dn * 16384], tid);
    }
    __builtin_amdgcn_s_setprio(1);
#pragma unroll
    for (int m = 0; m < 4; m++)
#pragma unroll
      for (int n = 0; n < 4; n++)
        acc[m][n] = __builtin_amdgcn_mfma_f32_16x16x32_bf16(af[m], bfv[n],
                                                            acc[m][n], 0, 0, 0);
    __builtin_amdgcn_s_setprio(0);

    // ---- phase 1: A frags m4..7; stage B(t+2); A_F32: cvt+ds_write ----
#pragma unroll
    for (int m = 0; m < 4; m++) {
      int row = wr * 128 + (m + 4) * 16 + lr;
      af[m] = *(const bf16x8*)&la[swzg(row, lh) * 8];
    }
    if (doPre) stage_half(B + (size_t)(t + 2) * 32, K, &lds[dn * 16384 + 8192], tid);
    if constexpr (A_F32) {
      if (doPre) {
        u16* dstA = &lds[dn * 16384];
        u32x4 w0;
        w0[0] = pk2(pre0[0], pre0[1]);
        w0[1] = pk2(pre0[2], pre0[3]);
        w0[2] = pk2(pre1[0], pre1[1]);
        w0[3] = pk2(pre1[2], pre1[3]);
        *(u32x4*)&dstA[tid * 8] = w0;
        int g = 512 + tid, row, ks;
        g2rk(g, row, ks);
        cvt_write_granule(A32 + (size_t)row * K + (t + 2) * 32 + ks * 8,
                          &dstA[g * 8]);
      }
    }
    __builtin_amdgcn_s_setprio(1);
#pragma unroll
    for (int m = 0; m < 4; m++)
#pragma unroll
      for (int n = 0; n < 4; n++)
        acc[m + 4][n] = __builtin_amdgcn_mfma_f32_16x16x32_bf16(
            af[m], bfv[n], acc[m + 4][n], 0, 0, 0);
    __builtin_amdgcn_s_setprio(0);

    // ---- tile boundary: counted vmcnt (loads for t+2 stay in flight) ----
    if constexpr (A_F32) {
      if (doPre)
        asm volatile("s_waitcnt vmcnt(2) lgkmcnt(0)" ::: "memory");
      else if (t + 1 < nt)
        asm volatile("s_waitcnt vmcnt(0) lgkmcnt(0)" ::: "memory");
    } else {
      if (doPre)
        asm volatile("s_waitcnt vmcnt(4)" ::: "memory");
      else if (t + 1 < nt)
        asm volatile("s_waitcnt vmcnt(0)" ::: "memory");
    }
    if (t + 1 < nt) __builtin_amdgcn_s_barrier();
    if (++d == 3) d = 0;
  }

  // ---- epilogue: C/D layout col=lane&15, row=(lane>>4)*4+reg ----
  if constexpr (TRANSV) {
    // write C^T per 2048-row batch: vhT[b][col][s], s = row % 2048.
    u16* Ch = (u16*)Cp;
#pragma unroll
    for (int m = 0; m < 8; m++) {
      int row0 = m0 + wr * 128 + m * 16 + lh * 4;
      int b = row0 >> 11, s = row0 & 2047;
#pragma unroll
      for (int n = 0; n < 4; n++) {
        int col = n0 + wc * 64 + n * 16 + lr;
        float v0 = acc[m][n][0] * scale, v1 = acc[m][n][1] * scale;
        float v2 = acc[m][n][2] * scale, v3 = acc[m][n][3] * scale;
        if constexpr (HAS_BIAS) {
          float bb = bias[col];
          v0 += bb; v1 += bb; v2 += bb; v3 += bb;
        }
        u32x2 p;
        p[0] = pk2(v0, v1);
        p[1] = pk2(v2, v3);
        *(u32x2*)&Ch[((size_t)b << 21) + ((size_t)col << 11) + s] = p;
      }
    }
  } else if constexpr (SMODE == 1) {
    // scores: write exp(score) bf16 (unnormalized) + deterministic partial
    // row sums: slot = nblk*4 + wc, each [bz][slot][row] written once.
    u16* Ch = (u16*)Cp + (size_t)bz * Cz;
    const int slot = (n0 >> 8) * 4 + wc;  // 0..31
    float* part = rsum + (((size_t)bz * 32 + slot) << 11);
#pragma unroll
    for (int m = 0; m < 8; m++) {
#pragma unroll
      for (int j = 0; j < 4; j++) {
        int row = m0 + wr * 128 + m * 16 + lh * 4 + j;
        float ls = 0.f;
#pragma unroll
        for (int n = 0; n < 4; n++) {
          int col = n0 + wc * 64 + n * 16 + lr;
          float e = __expf(acc[m][n][j] * scale);
          ls += e;
          Ch[(size_t)row * N + col] = f2bf(e);
        }
        // reduce over the 16-lane col group (lane = lh*16 + lr)
        ls += __shfl_xor(ls, 1, 64);
        ls += __shfl_xor(ls, 2, 64);
        ls += __shfl_xor(ls, 4, 64);
        ls += __shfl_xor(ls, 8, 64);
        if (lr == 0) part[row] = ls;  // plain store, L2-resident
      }
    }
  } else {
    float* Cf = nullptr;
    u16* Ch = nullptr;
    if constexpr (OUT_F32)
      Cf = (float*)Cp + (size_t)bz * Cz;
    else
      Ch = (u16*)Cp + (size_t)bz * Cz;
#pragma unroll
    for (int m = 0; m < 8; m++) {
#pragma unroll
      for (int j = 0; j < 4; j++) {
        int row = m0 + wr * 128 + m * 16 + lh * 4 + j;
        float inv = 1.f;
        if constexpr (SMODE == 2) inv = 1.0f / rsum[((size_t)bz << 11) + row];
#pragma unroll
        for (int n = 0; n < 4; n++) {
          int col = n0 + wc * 64 + n * 16 + lr;
          float val = acc[m][n][j] * scale;
          if constexpr (SMODE == 2) val *= inv;
          if constexpr (HAS_BIAS) val += bias[col];
          if constexpr (RESID) val += resid[(size_t)row * N + col];
          if constexpr (OUT_F32)
            Cf[(size_t)row * N + col] = val;
          else
            Ch[(size_t)row * N + col] = f2bf(val);
        }
      }
    }
  }
}

// ---------------------------------------------------------------------------
// fused weight cvt: 4 x [1024x1024] fp32 -> contiguous bf16 (one launch)
// ---------------------------------------------------------------------------
__global__ __launch_bounds__(256) void cvt8w(const float* __restrict__ w0,
                                             const float* __restrict__ w1,
                                             const float* __restrict__ w2,
                                             const float* __restrict__ w3,
                                             u16* __restrict__ out) {
  const int wsel = blockIdx.x >> 9;
  const float* in = wsel == 0 ? w0 : wsel == 1 ? w1 : wsel == 2 ? w2 : w3;
  const size_t i = ((size_t)(blockIdx.x & 511) * 256 + threadIdx.x) * 8;
  f32x4 a = *(const f32x4*)&in[i];
  f32x4 b = *(const f32x4*)&in[i + 4];
  u32x4 w;
  w[0] = pk2(a[0], a[1]);
  w[1] = pk2(a[2], a[3]);
  w[2] = pk2(b[0], b[1]);
  w[3] = pk2(b[2], b[3]);
  *(u32x4*)&out[(size_t)wsel * 1048576 + i] = w;
}

// ---------------------------------------------------------------------------
// fold 32 partial row sums -> rowsum.  part[bz][s][row], coalesced in row.
// ---------------------------------------------------------------------------
__global__ __launch_bounds__(256) void reduce32(const float* __restrict__ part,
                                                float* __restrict__ rowsum) {
  const int g = blockIdx.x * 256 + threadIdx.x;  // 0..16383
  const int bz = g >> 11, r = g & 2047;
  const float* p = part + (((size_t)bz * 32) << 11) + r;
  float s = 0.f;
#pragma unroll
  for (int k = 0; k < 32; k++) s += p[(size_t)k << 11];
  rowsum[g] = s;
}

// ---------------------------------------------------------------------------
// LayerNorm rows of 1024 bf16 -> fp32 d_out  (x stored bf16: halves traffic)
// ---------------------------------------------------------------------------
__global__ __launch_bounds__(256) void ln_rows_bf16(const u16* __restrict__ x,
                                                    const float* __restrict__ gamma,
                                                    const float* __restrict__ beta,
                                                    float* __restrict__ out) {
  const size_t base = (size_t)blockIdx.x * 1024;
  const int tid = threadIdx.x, lane = tid & 63, wv = tid >> 6;
  bf16x4 h4 = *(const bf16x4*)&x[base + tid * 4];
  float v[4];
#pragma unroll
  for (int u = 0; u < 4; u++) v[u] = bf2f((u16)h4[u]);
  float s = v[0] + v[1] + v[2] + v[3];
  float q = v[0] * v[0] + v[1] * v[1] + v[2] * v[2] + v[3] * v[3];
#pragma unroll
  for (int o = 32; o; o >>= 1) {
    s += __shfl_xor(s, o, 64);
    q += __shfl_xor(q, o, 64);
  }
  __shared__ float rs[4], rq[4];
  if (lane == 0) {
    rs[wv] = s;
    rq[wv] = q;
  }
  __syncthreads();
  s = rs[0] + rs[1] + rs[2] + rs[3];
  q = rq[0] + rq[1] + rq[2] + rq[3];
  float mean = s * (1.f / 1024.f);
  float var = q * (1.f / 1024.f) - mean * mean;
  float rstd = rsqrtf(var + 1e-5f);
  f32x4 g = *(const f32x4*)&gamma[tid * 4];
  f32x4 b = *(const f32x4*)&beta[tid * 4];
  f32x4 o;
#pragma unroll
  for (int u = 0; u < 4; u++) o[u] = (v[u] - mean) * rstd * g[u] + b[u];
  *(f32x4*)&out[base + tid * 4] = o;
}

// ---------------------------------------------------------------------------
extern "C" void kernel_launch(void* const* d_in, const int* in_sizes, int n_in,
                              void* d_out, int out_size, void* d_ws,
                              size_t ws_size, hipStream_t stream) {
  (void)in_sizes; (void)n_in; (void)out_size; (void)ws_size;
  const float* q = (const float*)d_in[0];
  const float* k = (const float*)d_in[1];
  const float* v = (const float*)d_in[2];
  const float* Wq = (const float*)d_in[3];
  const float* Wk = (const float*)d_in[4];
  const float* bk = (const float*)d_in[5];
  const float* Wv = (const float*)d_in[6];
  const float* bv = (const float*)d_in[7];
  const float* Wo = (const float*)d_in[8];
  const float* bo = (const float*)d_in[9];
  const float* gamma = (const float*)d_in[10];
  const float* beta = (const float*)d_in[11];
  float* out = (float*)d_out;

  char* ws = (char*)d_ws;
  const size_t SZ_QKV = (size_t)16384 * 1024 * 2;  // 32 MiB
  u16* qh = (u16*)(ws);
  u16* kh = (u16*)(ws + SZ_QKV);
  float* partial = (float*)(ws + 2 * SZ_QKV);            // 2 MB in dead vh slot
  float* rowsum = (float*)(ws + 2 * SZ_QKV + 2097152);   // 64 KB
  u16* vhT = (u16*)(ws + 3 * SZ_QKV);       // [b][1024][2048], written by V-proj
  u16* probs = (u16*)(ws + 4 * SZ_QKV);     // 64 MiB, alive scores->PV
  u16* xbuf = (u16*)(ws + 4 * SZ_QKV);      // bf16 x, overlays probs (dead)
  u16* attn = qh;                           // overlays qh (dead after scores)
  u16* Wqb = (u16*)(ws + 4 * SZ_QKV + (size_t)67108864);
  u16* Wkb = Wqb + 1048576;
  u16* Wvb = Wkb + 1048576;
  u16* Wob = Wvb + 1048576;

  // all 4 weights -> bf16, one launch (dsts contiguous from Wqb)
  cvt8w<<<2048, 256, 0, stream>>>(Wq, Wk, Wv, Wo, Wqb);

  // projections: fp32 A fused-cvt inside GEMM; [16384,1024] x [1024,1024]^T
  dim3 gp(4, 64, 1);  // 256 blocks of 256x256
  gemm_bt<true, false, false, false, false, 0><<<gp, 512, 0, stream>>>(
      q, Wqb, nullptr, nullptr, nullptr, qh, 1024, 1024, 0, 0, 0, 0.125f);
  gemm_bt<true, true, false, false, false, 0><<<gp, 512, 0, stream>>>(
      k, Wkb, bk, nullptr, nullptr, kh, 1024, 1024, 0, 0, 0, 1.0f);
  // V-proj writes vhT directly (transposed epilogue)
  gemm_bt<true, true, false, false, true, 0><<<gp, 512, 0, stream>>>(
      v, Wvb, bv, nullptr, nullptr, vhT, 1024, 1024, 0, 0, 0, 1.0f);

  // scores = exp(qh @ kh^T) per batch -> probs (bf16) + deterministic
  // partial row sums (no atomics); reduce32 folds partials -> rowsum.
  gemm_bt<false, false, false, false, false, 1><<<dim3(8, 8, 8), 512, 0,
                                                  stream>>>(
      qh, kh, nullptr, nullptr, partial, probs, 2048, 1024, 2097152LL,
      2097152LL, 4194304LL, 1.0f);
  reduce32<<<64, 256, 0, stream>>>(partial, rowsum);

  // attn = (probs @ vhT^T) / rowsum per batch
  gemm_bt<false, false, false, false, false, 2><<<dim3(4, 8, 8), 512, 0,
                                                  stream>>>(
      probs, vhT, nullptr, nullptr, rowsum, attn, 1024, 2048, 4194304LL,
      2097152LL, 2097152LL, 1.0f);

  // x = attn @ Wo^T + bo + q  -> bf16 xbuf (halves x traffic; LN reads bf16)
  gemm_bt<false, true, true, false, false, 0><<<dim3(4, 64, 1), 512, 0,
                                                stream>>>(
      attn, Wob, bo, q, nullptr, xbuf, 1024, 1024, 0, 0, 0, 1.0f);

  // LayerNorm -> out
  ln_rows_bf16<<<16384, 256, 0, stream>>>(xbuf, gamma, beta, out);
}